// Round 14
// baseline (71.683 us; speedup 1.0000x reference)
//
#include <hip/hip_runtime.h>
#include <math.h>

// Problem constants
#define BB 16384
#define TT 99
#define RR 10
#define LL 3
#define TILE 20          // 99 = 4*20 + 19; small tile -> LDS 28.8KB -> 2 blocks/CU
#define RPW 16           // rows per wave (4 lanes per row)
#define WPB 2            // waves per block (128 threads, 32 rows/block)

// quad_perm DPP broadcast: every lane of a 4-lane quad gets quad-lane Q's value.
#define QPB(v, Q) __int_as_float(__builtin_amdgcn_mov_dpp(                    \
    __float_as_int(v), (Q) * 0x55, 0xF, 0xF, true))

// tanh(x) = 1 - 2/(exp(2x)+1); exact limits at +-inf.
__device__ __forceinline__ float fast_tanh(float x) {
    float e = __expf(2.0f * x);
    return fmaf(-2.0f, __builtin_amdgcn_rcpf(e + 1.0f), 1.0f);
}

// ==================== fused recurrence + epilogue ====================
// R14 = R13's DPP gather (VALU pipe, no DS contention) + R12's TLP (2 waves/
// SIMD): block=128 (2 waves), TILE=20 -> 28.8KB LDS -> 2 blocks/CU -> grid
// 512 blocks = 8 waves/CU. The co-resident wave hides the per-step serial
// chain that capped R13 at 1 wave/SIMD (occupancy 9.4%, VALUBusy 30%).
// No barriers: each wave owns its rows + LDS slice (same-wave DS ordering).
__global__ __launch_bounds__(128, 2)
void rnn_fused_kernel(const int* __restrict__ tok_ids,
                      const float* __restrict__ labels,
                      const float* __restrict__ emb,
                      const float* __restrict__ W,
                      const float* __restrict__ U,
                      const float* __restrict__ bvec,
                      const float* __restrict__ Wo,
                      const float* __restrict__ bo,
                      float* __restrict__ states_out,
                      float* __restrict__ probs_out,
                      float* __restrict__ ws)
{
    __shared__ __align__(16) float          s_st[WPB][RPW * TILE * RR]; // 25,600 B
    __shared__                unsigned char s_code[WPB][RPW * 100];     //  3,200 B

    const int tid = threadIdx.x;
    const int w   = tid >> 6;
    const int l   = tid & 63;
    const int r4  = l >> 2;                   // row within wave (0..15)
    const int q   = l & 3;                    // unit slot (0..3)
    const int rowbase = blockIdx.x * (WPB * RPW) + w * RPW;

    // ---- preamble: classify tokens+labels -> code byte (sel<<2)|y ----
#pragma unroll 1
    for (int g = 0; g < 5; ++g) {
#pragma unroll
        for (int u = 0; u < 5; ++u) {
            const int p = l + 64 * (g * 5 + u);
            if (p < RPW * TT) {
                const size_t gi = (size_t)rowbase * TT + p;   // contiguous
                const int   tk  = tok_ids[gi];
                const float la1 = labels[gi * LL + 1];
                const float la2 = labels[gi * LL + 2];
                const int   y   = (la1 > 0.5f) ? 1 : ((la2 > 0.5f) ? 2 : 0);
                const int   r   = p / TT;
                s_code[w][r * 100 + (p - r * TT)] = (unsigned char)((tk << 2) | y);
            }
        }
    }

    // ---- per-lane weight columns (lane-varying -> VGPR-resident) ----
    const int uA = q;
    const int uB = 4 + q;
    const int uC = (q < 2) ? 8 + q : q;       // slots 2,3: duplicate (unused)
    float UA[RR], UB[RR], UC[RR];
    float cA1 = bvec[uA], cA2 = cA1;
    float cB1 = bvec[uB], cB2 = cB1;
    float cC1 = bvec[uC], cC2 = cC1;
#pragma unroll
    for (int i = 0; i < RR; ++i) {
        UA[i] = U[i * RR + uA];
        UB[i] = U[i * RR + uB];
        UC[i] = U[i * RR + uC];
        const float wA = W[i * RR + uA];
        const float wB = W[i * RR + uB];
        const float wC = W[i * RR + uC];
        const float e1 = emb[RR + i];         // token-1 row
        const float e2 = emb[2 * RR + i];     // token-2 row
        cA1 = fmaf(e1, wA, cA1); cA2 = fmaf(e2, wA, cA2);
        cB1 = fmaf(e1, wB, cB1); cB2 = fmaf(e2, wB, cB2);
        cC1 = fmaf(e1, wC, cC1); cC2 = fmaf(e2, wC, cC2);
    }

    float hoA = 0.0f, hoB = 0.0f, hoC = 0.0f;
    float loss = 0.0f;
    int   corr = 0;
    int code = (int)s_code[w][r4 * 100];      // prefetch t=0

#pragma unroll 1
    for (int kt = 0; kt < 5; ++kt) {
        const int t0   = kt * TILE;
        const int tlen = (t0 + TILE <= TT) ? TILE : (TT - t0);   // 20,20,20,20,19

        // ================== sequential phase: tlen steps ==================
#pragma unroll 1
        for (int tt = 0; tt < tlen; ++tt) {
            const int t   = t0 + tt;
            const int cur = code;
            const int tn  = (t + 1 < TT) ? t + 1 : t;
            code = (int)s_code[w][r4 * 100 + tn];     // prefetch next (off-chain)
            const int sel = cur >> 2;

            // gather full h: 10 quad_perm broadcasts (VALU pipe)
            float h[RR];
            h[0] = QPB(hoA, 0); h[1] = QPB(hoA, 1);
            h[2] = QPB(hoA, 2); h[3] = QPB(hoA, 3);
            h[4] = QPB(hoB, 0); h[5] = QPB(hoB, 1);
            h[6] = QPB(hoB, 2); h[7] = QPB(hoB, 3);
            h[8] = QPB(hoC, 0); h[9] = QPB(hoC, 1);

            const bool is1 = (sel == 1);
            float aA = is1 ? cA1 : cA2;
            float aB = is1 ? cB1 : cB2;
            float aC = is1 ? cC1 : cC2;
#pragma unroll
            for (int i = 0; i < RR; ++i) {
                aA = fmaf(h[i], UA[i], aA);
                aB = fmaf(h[i], UB[i], aB);
                aC = fmaf(h[i], UC[i], aC);
            }
            const float hnA = fast_tanh(aA);
            const float hnB = fast_tanh(aB);
            const float hnC = fast_tanh(aC);
            if (sel != 0) { hoA = hnA; hoB = hnB; hoC = hnC; }  // Keras masking

            // stage own units (fire-and-forget b32)
            float* sp = &s_st[w][(r4 * TILE + tt) * RR];
            sp[q]     = hoA;
            sp[4 + q] = hoB;
            if (q < 2) sp[8 + q] = hoC;
        }

        // ================== parallel phase (per tile) ==================
        const int fl2 = tlen * (RR / 2);       // float2 per row: 100 or 95

        // ---- flush states: 16 rows x tlen*10 floats, coalesced float2 ----
#pragma unroll 1
        for (int i = 0; i < 25; ++i) {
            const int p = l + 64 * i;
            if (p < RPW * fl2) {
                const int r = p / fl2;
                const int m = p - r * fl2;
                const float2 v = *reinterpret_cast<const float2*>(
                    &s_st[w][r * (TILE * RR) + 2 * m]);
                *reinterpret_cast<float2*>(
                    &states_out[(size_t)(rowbase + r) * (TT * RR)
                                + (size_t)t0 * RR + 2 * m]) = v;
            }
        }

        // ---- fused epilogue: 16*tlen (row,step) pairs, wave-parallel ----
#pragma unroll 1
        for (int i = 0; i < 5; ++i) {
            const int p = l + 64 * i;
            if (p < RPW * tlen) {
                const int r  = p / tlen;
                const int t2 = p - r * tlen;
                const size_t idx = (size_t)(rowbase + r) * TT + t0 + t2;

                // h from LDS via float2 (5x ds_read_b64)
                const float* hp = &s_st[w][(r * TILE + t2) * RR];
                float h0[RR];
#pragma unroll
                for (int j = 0; j < RR; j += 2) {
                    const float2 v = *reinterpret_cast<const float2*>(hp + j);
                    h0[j] = v.x; h0[j + 1] = v.y;
                }
                float l0 = bo[0], l1 = bo[1], l2 = bo[2];
#pragma unroll
                for (int j = 0; j < RR; ++j) {
                    l0 = fmaf(h0[j], Wo[j * LL + 0], l0);
                    l1 = fmaf(h0[j], Wo[j * LL + 1], l1);
                    l2 = fmaf(h0[j], Wo[j * LL + 2], l2);
                }
                const float e0 = __expf(l0), e1 = __expf(l1), e2 = __expf(l2);
                const float S  = e0 + e1 + e2;
                const float rs = __builtin_amdgcn_rcpf(S);
                probs_out[idx * LL + 0] = e0 * rs;
                probs_out[idx * LL + 1] = e1 * rs;
                probs_out[idx * LL + 2] = e2 * rs;

                const int y = (int)s_code[w][r * 100 + t0 + t2] & 3;

                // loss: -log(clip(p_y, 1e-7, 1)) == min(logS - l_y, -log(1e-7))
                const float ly = (y == 0) ? l0 : ((y == 1) ? l1 : l2);
                loss += fminf(__logf(S) - ly, 16.11809565f);

                // accuracy: argmax(logits) == argmax(probs)
                int ap = 0; float pm = l0;
                if (l1 > pm) { ap = 1; pm = l1; }
                if (l2 > pm) { ap = 2; }
                corr += (ap == y) ? 1 : 0;
            }
        }
        // next tile reuses s_st: same-wave DS ordering guarantees safety
    }

    // ---- wave reduction -> one partial per wave (deterministic) ----
    float ls = loss, cs = (float)corr;
#pragma unroll
    for (int off = 32; off > 0; off >>= 1) {
        ls += __shfl_down(ls, off, 64);
        cs += __shfl_down(cs, off, 64);
    }
    if (l == 0) {
        const int wid = blockIdx.x * WPB + w;     // 0..1023
        ws[wid]        = ls;
        ws[1024 + wid] = cs;
    }
}

__global__ __launch_bounds__(256)
void finalize_kernel(const float* __restrict__ ws, float* __restrict__ out_tail)
{
    __shared__ float sl[4], sc[4];
    const int t = threadIdx.x;
    float ls = 0.0f, cs = 0.0f;
#pragma unroll
    for (int i = 0; i < 4; ++i) {
        ls += ws[t + 256 * i];
        cs += ws[1024 + t + 256 * i];
    }
#pragma unroll
    for (int off = 32; off > 0; off >>= 1) {
        ls += __shfl_down(ls, off, 64);
        cs += __shfl_down(cs, off, 64);
    }
    if ((t & 63) == 0) { sl[t >> 6] = ls; sc[t >> 6] = cs; }
    __syncthreads();
    if (t == 0) {
        const float L = sl[0] + sl[1] + sl[2] + sl[3];
        const float C = sc[0] + sc[1] + sc[2] + sc[3];
        const float inv = 1.0f / (float)((size_t)BB * TT);
        out_tail[0] = C * inv;   // accuracy
        out_tail[1] = L * inv;   // loss
    }
}

extern "C" void kernel_launch(void* const* d_in, const int* in_sizes, int n_in,
                              void* d_out, int out_size, void* d_ws, size_t ws_size,
                              hipStream_t stream)
{
    const int*   tok    = (const int*)  d_in[0];
    const float* labels = (const float*)d_in[1];
    // d_in[2] = mask (unused by reference math)
    const float* emb = (const float*)d_in[3];
    const float* W   = (const float*)d_in[4];
    const float* U   = (const float*)d_in[5];
    const float* bv  = (const float*)d_in[6];
    const float* Wo  = (const float*)d_in[7];
    const float* bo  = (const float*)d_in[8];

    float* out    = (float*)d_out;
    float* states = out;                                  // [B,T,10]
    float* probs  = out + (size_t)BB * TT * RR;           // [B,T,3]
    float* tail   = out + (size_t)BB * TT * (RR + LL);    // accuracy, loss
    float* ws     = (float*)d_ws;                         // 2048 floats used

    rnn_fused_kernel<<<BB / (WPB * RPW), 128, 0, stream>>>(
        tok, labels, emb, W, U, bv, Wo, bo, states, probs, ws);
    finalize_kernel<<<1, 256, 0, stream>>>(ws, tail);
}

// Round 15
// 51.113 us; speedup vs baseline: 1.4024x; 1.4024x over previous
//
#include <hip/hip_runtime.h>
#include <math.h>

// Problem constants
#define BB 16384
#define TT 99
#define RR 10
#define LL 3
#define TILE 33          // 99 = 3*33; ALL divisors compile-time (R14 lesson)
#define RPW 8            // rows per wave (8 lanes per row) -> 2048 waves = 8/CU
#define WPB 4            // waves per block (256 threads)

// DPP cross-lane (VALU pipe; R12's 10 ds_bpermute/step hammered the DS pipe):
// QP(v,j): every lane of a 4-lane quad gets quad-lane j's value.
// HMIR(v): mirror within each 8-lane half-row (lane g <-> 7-g) = our group!
#define QP(v, j) __int_as_float(__builtin_amdgcn_mov_dpp(                     \
    __float_as_int(v), (j) * 0x55, 0xF, 0xF, true))
#define HMIR(v)  __int_as_float(__builtin_amdgcn_mov_dpp(                     \
    __float_as_int(v), 0x141, 0xF, 0xF, true))

// tanh(x) = 1 - 2/(exp(2x)+1); exact limits at +-inf.
__device__ __forceinline__ float fast_tanh(float x) {
    float e = __expf(2.0f * x);
    return fmaf(-2.0f, __builtin_amdgcn_rcpf(e + 1.0f), 1.0f);
}

// ==================== fused recurrence + epilogue ====================
// 8 lanes/row (lane g owns unit g; lanes with (g&3)<2 also compute units
// 8/9 -- duplicated in BOTH quads so qp(hoB,0/1) serves every lane).
// Full-h gather = 11 DPP ops, order quad-dependent; each lane's U
// coefficients are loaded pre-permuted (ord[]) so order costs nothing.
// DS ops/step: 13 (R12) -> 3. Grid 512x256 = 2048 waves = 8 waves/CU.
// No barriers: each wave owns its rows + LDS slice.
__global__ __launch_bounds__(256, 2)
void rnn_fused_kernel(const int* __restrict__ tok_ids,
                      const float* __restrict__ labels,
                      const float* __restrict__ emb,
                      const float* __restrict__ W,
                      const float* __restrict__ U,
                      const float* __restrict__ bvec,
                      const float* __restrict__ Wo,
                      const float* __restrict__ bo,
                      float* __restrict__ states_out,
                      float* __restrict__ probs_out,
                      float* __restrict__ ws)
{
    __shared__ __align__(16) float          s_st[WPB][RPW * TILE * RR]; // 42,240 B
    __shared__                unsigned char s_code[WPB][RPW * 100];     //  3,200 B

    const int tid = threadIdx.x;
    const int w   = tid >> 6;
    const int l   = tid & 63;
    const int r8  = l >> 3;                   // row within wave (0..7)
    const int g   = l & 7;                    // unit slot (0..7)
    const int rowbase = blockIdx.x * (WPB * RPW) + w * RPW;

    // ---- preamble: classify tokens+labels -> code byte (sel<<2)|y ----
#pragma unroll 1
    for (int i = 0; i < 13; ++i) {
        const int p = l + 64 * i;
        if (p < RPW * TT) {
            const size_t gi = (size_t)rowbase * TT + p;   // contiguous
            const int   tk  = tok_ids[gi];
            const float la1 = labels[gi * LL + 1];
            const float la2 = labels[gi * LL + 2];
            const int   y   = (la1 > 0.5f) ? 1 : ((la2 > 0.5f) ? 2 : 0);
            const int   r   = p / TT;                     // compile-time divisor
            s_code[w][r * 100 + (p - r * TT)] = (unsigned char)((tk << 2) | y);
        }
    }

    // ---- per-lane gather order (quad-dependent) + weight coefficients ----
    // gather delivers: hg[0..3] = own-quad units, hg[4..7] = mirrored other
    // quad. quad0: ord = {0,1,2,3, 7,6,5,4}; quad1: ord = {4,5,6,7, 3,2,1,0}.
    const int qpar = g >> 2;
    int ord[8];
#pragma unroll
    for (int j = 0; j < 4; ++j) {
        ord[j]     = qpar ? 4 + j : j;
        ord[4 + j] = qpar ? 3 - j : 7 - j;
    }
    const int jA = g;                              // own hoA unit
    const int jB = ((g & 3) < 2) ? 8 + (g & 3) : 8; // hoB unit (dup for others)

    float UA[RR], UB[RR];
#pragma unroll
    for (int k2 = 0; k2 < 8; ++k2) {
        UA[k2] = U[ord[k2] * RR + jA];
        UB[k2] = U[ord[k2] * RR + jB];
    }
    UA[8] = U[8 * RR + jA]; UA[9] = U[9 * RR + jA];
    UB[8] = U[8 * RR + jB]; UB[9] = U[9 * RR + jB];

    float cA1 = bvec[jA], cA2 = cA1, cB1 = bvec[jB], cB2 = cB1;
#pragma unroll
    for (int i = 0; i < RR; ++i) {
        const float e1 = emb[RR + i];          // token-1 row
        const float e2 = emb[2 * RR + i];      // token-2 row
        const float wA = W[i * RR + jA];
        const float wB = W[i * RR + jB];
        cA1 = fmaf(e1, wA, cA1); cA2 = fmaf(e2, wA, cA2);
        cB1 = fmaf(e1, wB, cB1); cB2 = fmaf(e2, wB, cB2);
    }

    float hoA = 0.0f, hoB = 0.0f;
    float loss = 0.0f;
    int   corr = 0;
    int code = (int)s_code[w][r8 * 100];      // prefetch t=0 (8-lane broadcast)

#pragma unroll 1
    for (int k = 0; k < 3; ++k) {
        // ================== sequential phase: 33 steps ==================
#pragma unroll 1
        for (int tt = 0; tt < TILE; ++tt) {
            const int t   = k * TILE + tt;
            const int cur = code;
            const int tn  = (t + 1 < TT) ? t + 1 : t;
            code = (int)s_code[w][r8 * 100 + tn];     // prefetch next (off-chain)
            const int sel = cur >> 2;

            // gather full h: 11 DPP ops (VALU pipe, zero DS)
            float hg[RR];
            hg[0] = QP(hoA, 0); hg[1] = QP(hoA, 1);
            hg[2] = QP(hoA, 2); hg[3] = QP(hoA, 3);
            const float mr = HMIR(hoA);
            hg[4] = QP(mr, 0);  hg[5] = QP(mr, 1);
            hg[6] = QP(mr, 2);  hg[7] = QP(mr, 3);
            hg[8] = QP(hoB, 0); hg[9] = QP(hoB, 1);

            const bool is1 = (sel == 1);
            float aA0 = is1 ? cA1 : cA2, aB0 = is1 ? cB1 : cB2;
            float aA1 = 0.0f, aB1 = 0.0f;
#pragma unroll
            for (int i = 0; i < 5; ++i) {      // split chains: 2x5 FMA deep
                aA0 = fmaf(hg[i],     UA[i],     aA0);
                aA1 = fmaf(hg[5 + i], UA[5 + i], aA1);
                aB0 = fmaf(hg[i],     UB[i],     aB0);
                aB1 = fmaf(hg[5 + i], UB[5 + i], aB1);
            }
            const float hnA = fast_tanh(aA0 + aA1);
            const float hnB = fast_tanh(aB0 + aB1);
            if (sel != 0) { hoA = hnA; hoB = hnB; }   // Keras masking: carry h

            // stage own units (fire-and-forget; 2 DS writes)
            float* sp = &s_st[w][(r8 * TILE + tt) * RR];
            sp[g] = hoA;
            if (g < 2) sp[8 + g] = hoB;        // quad0 owners write units 8,9
        }

        // ================== parallel phase (per tile) ==================
        // ---- flush states: 8 rows x 330 floats = 1320 float2, coalesced ----
#pragma unroll 1
        for (int i = 0; i < 21; ++i) {
            const int p = l + 64 * i;
            if (p < 1320) {
                const int r = p / 165;                 // compile-time divisor
                const int m = p - r * 165;
                const float2 v = *reinterpret_cast<const float2*>(
                    &s_st[w][r * (TILE * RR) + 2 * m]);
                *reinterpret_cast<float2*>(
                    &states_out[(size_t)(rowbase + r) * (TT * RR)
                                + (size_t)k * (TILE * RR) + 2 * m]) = v;
            }
        }

        // ---- fused epilogue: 264 (row,step) pairs, wave-parallel ----
#pragma unroll 1
        for (int i = 0; i < 5; ++i) {
            const int p = l + 64 * i;
            if (p < RPW * TILE) {
                const int r  = p / TILE;               // compile-time divisor
                const int t2 = p - r * TILE;
                const size_t idx = (size_t)(rowbase + r) * TT + k * TILE + t2;

                const float* hp = &s_st[w][(r * TILE + t2) * RR];
                float h0[RR];
#pragma unroll
                for (int j = 0; j < RR; j += 2) {
                    const float2 v = *reinterpret_cast<const float2*>(hp + j);
                    h0[j] = v.x; h0[j + 1] = v.y;
                }
                float l0 = bo[0], l1 = bo[1], l2 = bo[2];
#pragma unroll
                for (int j = 0; j < RR; ++j) {
                    l0 = fmaf(h0[j], Wo[j * LL + 0], l0);
                    l1 = fmaf(h0[j], Wo[j * LL + 1], l1);
                    l2 = fmaf(h0[j], Wo[j * LL + 2], l2);
                }
                const float e0 = __expf(l0), e1 = __expf(l1), e2 = __expf(l2);
                const float S  = e0 + e1 + e2;
                const float rs = __builtin_amdgcn_rcpf(S);
                probs_out[idx * LL + 0] = e0 * rs;
                probs_out[idx * LL + 1] = e1 * rs;
                probs_out[idx * LL + 2] = e2 * rs;

                const int y = (int)s_code[w][r * 100 + k * TILE + t2] & 3;

                // loss: -log(clip(p_y, 1e-7, 1)) == min(logS - l_y, -log(1e-7))
                const float ly = (y == 0) ? l0 : ((y == 1) ? l1 : l2);
                loss += fminf(__logf(S) - ly, 16.11809565f);

                // accuracy: argmax(logits) == argmax(probs)
                int ap = 0; float pm = l0;
                if (l1 > pm) { ap = 1; pm = l1; }
                if (l2 > pm) { ap = 2; }
                corr += (ap == y) ? 1 : 0;
            }
        }
        // next tile reuses s_st: same-wave DS ordering guarantees safety
    }

    // ---- wave reduction -> one partial per wave (deterministic) ----
    float ls = loss, cs = (float)corr;
#pragma unroll
    for (int off = 32; off > 0; off >>= 1) {
        ls += __shfl_down(ls, off, 64);
        cs += __shfl_down(cs, off, 64);
    }
    if (l == 0) {
        const int wid = blockIdx.x * WPB + w;     // 0..2047
        ws[wid]        = ls;
        ws[2048 + wid] = cs;
    }
}

__global__ __launch_bounds__(256)
void finalize_kernel(const float* __restrict__ ws, float* __restrict__ out_tail)
{
    __shared__ float sl[4], sc[4];
    const int t = threadIdx.x;
    float ls = 0.0f, cs = 0.0f;
#pragma unroll
    for (int i = 0; i < 8; ++i) {
        ls += ws[t + 256 * i];
        cs += ws[2048 + t + 256 * i];
    }
#pragma unroll
    for (int off = 32; off > 0; off >>= 1) {
        ls += __shfl_down(ls, off, 64);
        cs += __shfl_down(cs, off, 64);
    }
    if ((t & 63) == 0) { sl[t >> 6] = ls; sc[t >> 6] = cs; }
    __syncthreads();
    if (t == 0) {
        const float L = sl[0] + sl[1] + sl[2] + sl[3];
        const float C = sc[0] + sc[1] + sc[2] + sc[3];
        const float inv = 1.0f / (float)((size_t)BB * TT);
        out_tail[0] = C * inv;   // accuracy
        out_tail[1] = L * inv;   // loss
    }
}

extern "C" void kernel_launch(void* const* d_in, const int* in_sizes, int n_in,
                              void* d_out, int out_size, void* d_ws, size_t ws_size,
                              hipStream_t stream)
{
    const int*   tok    = (const int*)  d_in[0];
    const float* labels = (const float*)d_in[1];
    // d_in[2] = mask (unused by reference math)
    const float* emb = (const float*)d_in[3];
    const float* W   = (const float*)d_in[4];
    const float* U   = (const float*)d_in[5];
    const float* bv  = (const float*)d_in[6];
    const float* Wo  = (const float*)d_in[7];
    const float* bo  = (const float*)d_in[8];

    float* out    = (float*)d_out;
    float* states = out;                                  // [B,T,10]
    float* probs  = out + (size_t)BB * TT * RR;           // [B,T,3]
    float* tail   = out + (size_t)BB * TT * (RR + LL);    // accuracy, loss
    float* ws     = (float*)d_ws;                         // 4096 floats used

    rnn_fused_kernel<<<BB / (WPB * RPW), 256, 0, stream>>>(
        tok, labels, emb, W, U, bv, Wo, bo, states, probs, ws);
    finalize_kernel<<<1, 256, 0, stream>>>(ws, tail);
}

// Round 16
// 49.637 us; speedup vs baseline: 1.4441x; 1.0297x over previous
//
#include <hip/hip_runtime.h>
#include <math.h>

// Problem constants
#define BB 16384
#define TT 99
#define RR 10
#define LL 3

// DPP cross-lane (VALU pipe):
// QP(v,j): every lane of a 4-lane quad gets quad-lane j's value.
// HMIR(v): mirror within each 8-lane half-row (lane g <-> 7-g).
#define QP(v, j) __int_as_float(__builtin_amdgcn_mov_dpp(                     \
    __float_as_int(v), (j) * 0x55, 0xF, 0xF, true))
#define HMIR(v)  __int_as_float(__builtin_amdgcn_mov_dpp(                     \
    __float_as_int(v), 0x141, 0xF, 0xF, true))

// tanh(x) = 1 - 2/(exp(2x)+1); exact limits at +-inf.
__device__ __forceinline__ float fast_tanh(float x) {
    float e = __expf(2.0f * x);
    return fmaf(-2.0f, __builtin_amdgcn_rcpf(e + 1.0f), 1.0f);
}

// ===================== K1: recurrence -> states (direct) =====================
// R15's verified 8-lane/row DPP core, with LDS staging/flush REMOVED: h is
// stored straight to global. Per-step store offset t*40B folds into the
// 13-bit immediate (unroll 11 -> const t), so stores are 1 instr each.
// Write-combining across consecutive steps fills L2 lines (step t and t+1 of
// a row are contiguous), so the 40B/row/step pattern streams at full rate.
// Lanes whose jB duplicates unit 8 all store the same value to the same
// address (benign collision, deterministic). Grid 512x256 = 2048 waves.
__global__ __launch_bounds__(256, 2)
void rnn_seq_kernel(const int* __restrict__ tok_ids,
                    const float* __restrict__ emb,
                    const float* __restrict__ W,
                    const float* __restrict__ U,
                    const float* __restrict__ bvec,
                    float* __restrict__ states_out)
{
    __shared__ unsigned char s_tk[4][8 * 100];   // 3.2 KB: token byte per (row,t)

    const int tid = threadIdx.x;
    const int w   = tid >> 6;
    const int l   = tid & 63;
    const int r8  = l >> 3;                   // row within wave (0..7)
    const int g   = l & 7;                    // unit slot (0..7)
    const int rowbase = blockIdx.x * 32 + w * 8;

    // ---- stage tokens (coalesced) ----
#pragma unroll
    for (int i = 0; i < 13; ++i) {
        const int p = l + 64 * i;
        if (p < 8 * TT) {
            const int r = p / TT;             // compile-time divisor
            s_tk[w][r * 100 + (p - r * TT)] =
                (unsigned char)tok_ids[(size_t)rowbase * TT + p];
        }
    }

    // ---- per-lane gather order (quad-dependent) + weight coefficients ----
    const int qpar = g >> 2;
    int ord[8];
#pragma unroll
    for (int j = 0; j < 4; ++j) {
        ord[j]     = qpar ? 4 + j : j;
        ord[4 + j] = qpar ? 3 - j : 7 - j;
    }
    const int jA = g;
    const int jB = ((g & 3) < 2) ? 8 + (g & 3) : 8;

    float UA[RR], UB[RR];
#pragma unroll
    for (int k2 = 0; k2 < 8; ++k2) {
        UA[k2] = U[ord[k2] * RR + jA];
        UB[k2] = U[ord[k2] * RR + jB];
    }
    UA[8] = U[8 * RR + jA]; UA[9] = U[9 * RR + jA];
    UB[8] = U[8 * RR + jB]; UB[9] = U[9 * RR + jB];

    float cA1 = bvec[jA], cA2 = cA1, cB1 = bvec[jB], cB2 = cB1;
#pragma unroll
    for (int i = 0; i < RR; ++i) {
        const float e1 = emb[RR + i];          // token-1 row
        const float e2 = emb[2 * RR + i];      // token-2 row
        const float wA = W[i * RR + jA];
        const float wB = W[i * RR + jB];
        cA1 = fmaf(e1, wA, cA1); cA2 = fmaf(e2, wA, cA2);
        cB1 = fmaf(e1, wB, cB1); cB2 = fmaf(e2, wB, cB2);
    }

    float hoA = 0.0f, hoB = 0.0f;
    float* outA = states_out + (size_t)(rowbase + r8) * (TT * RR) + jA;
    float* outB = states_out + (size_t)(rowbase + r8) * (TT * RR) + jB;

    int code = (int)s_tk[w][r8 * 100];        // prefetch t=0

#pragma unroll 11
    for (int t = 0; t < TT; ++t) {
        const int cur = code;
        const int tn  = (t + 1 < TT) ? t + 1 : t;
        code = (int)s_tk[w][r8 * 100 + tn];   // prefetch next (off-chain)

        // gather full h: 11 DPP ops (VALU pipe, zero DS)
        float hg[RR];
        hg[0] = QP(hoA, 0); hg[1] = QP(hoA, 1);
        hg[2] = QP(hoA, 2); hg[3] = QP(hoA, 3);
        const float mr = HMIR(hoA);
        hg[4] = QP(mr, 0);  hg[5] = QP(mr, 1);
        hg[6] = QP(mr, 2);  hg[7] = QP(mr, 3);
        hg[8] = QP(hoB, 0); hg[9] = QP(hoB, 1);

        const bool is1 = (cur == 1);
        float aA0 = is1 ? cA1 : cA2, aB0 = is1 ? cB1 : cB2;
        float aA1 = 0.0f, aB1 = 0.0f;
#pragma unroll
        for (int i = 0; i < 5; ++i) {          // split chains: 2x5 FMA deep
            aA0 = fmaf(hg[i],     UA[i],     aA0);
            aA1 = fmaf(hg[5 + i], UA[5 + i], aA1);
            aB0 = fmaf(hg[i],     UB[i],     aB0);
            aB1 = fmaf(hg[5 + i], UB[5 + i], aB1);
        }
        const float hnA = fast_tanh(aA0 + aA1);
        const float hnB = fast_tanh(aB0 + aB1);
        if (cur != 0) { hoA = hnA; hoB = hnB; }   // Keras masking: carry h

        // direct global stores (const t -> immediate offset, 1 instr each)
        outA[t * RR] = hoA;
        outB[t * RR] = hoB;
    }
}

// ===================== K2: epilogue (full occupancy) =====================
// Fully parallel over (b,t): dense+softmax+probs+loss+acc. Memory-bound.
__global__ __launch_bounds__(256)
void epilogue_kernel(const float* __restrict__ states,
                     const float* __restrict__ labels,
                     const float* __restrict__ Wo,
                     const float* __restrict__ bo,
                     float* __restrict__ probs_out,
                     float* __restrict__ ws)
{
    const int NT     = BB * TT;               // 1,622,016
    const int tid    = blockIdx.x * 256 + threadIdx.x;
    const int stride = 2048 * 256;

    float Wc0[RR], Wc1[RR], Wc2[RR];
#pragma unroll
    for (int j = 0; j < RR; ++j) {
        Wc0[j] = Wo[j * LL + 0];
        Wc1[j] = Wo[j * LL + 1];
        Wc2[j] = Wo[j * LL + 2];
    }
    const float b0 = bo[0], b1 = bo[1], b2 = bo[2];

    float loss = 0.0f;
    int   corr = 0;

#pragma unroll 1
    for (int idx = tid; idx < NT; idx += stride) {
        const float* hp = states + (size_t)idx * RR;   // 8B-aligned (40B stride)
        float h[RR];
#pragma unroll
        for (int j = 0; j < RR; j += 2) {
            const float2 v = *reinterpret_cast<const float2*>(hp + j);
            h[j] = v.x; h[j + 1] = v.y;
        }
        const float la1 = labels[(size_t)idx * LL + 1];
        const float la2 = labels[(size_t)idx * LL + 2];
        const int   y   = (la1 > 0.5f) ? 1 : ((la2 > 0.5f) ? 2 : 0);

        float l0 = b0, l1 = b1, l2 = b2;
#pragma unroll
        for (int j = 0; j < RR; ++j) {
            l0 = fmaf(h[j], Wc0[j], l0);
            l1 = fmaf(h[j], Wc1[j], l1);
            l2 = fmaf(h[j], Wc2[j], l2);
        }
        const float e0 = __expf(l0), e1 = __expf(l1), e2 = __expf(l2);
        const float S  = e0 + e1 + e2;
        const float rs = __builtin_amdgcn_rcpf(S);
        probs_out[(size_t)idx * LL + 0] = e0 * rs;
        probs_out[(size_t)idx * LL + 1] = e1 * rs;
        probs_out[(size_t)idx * LL + 2] = e2 * rs;

        // loss: -log(clip(p_y, 1e-7, 1)) == min(logS - l_y, -log(1e-7))
        const float ly = (y == 0) ? l0 : ((y == 1) ? l1 : l2);
        loss += fminf(__logf(S) - ly, 16.11809565f);

        // accuracy: argmax(logits) == argmax(probs) (monotonic, same ties)
        int ap = 0; float pm = l0;
        if (l1 > pm) { ap = 1; pm = l1; }
        if (l2 > pm) { ap = 2; }
        corr += (ap == y) ? 1 : 0;
    }

    // block reduction -> one partial pair per block (deterministic)
    __shared__ float sl[4], sc[4];
    float ls = loss, cs = (float)corr;
#pragma unroll
    for (int off = 32; off > 0; off >>= 1) {
        ls += __shfl_down(ls, off, 64);
        cs += __shfl_down(cs, off, 64);
    }
    if ((threadIdx.x & 63) == 0) { sl[threadIdx.x >> 6] = ls; sc[threadIdx.x >> 6] = cs; }
    __syncthreads();
    if (threadIdx.x == 0) {
        ws[blockIdx.x]        = sl[0] + sl[1] + sl[2] + sl[3];
        ws[2048 + blockIdx.x] = sc[0] + sc[1] + sc[2] + sc[3];
    }
}

__global__ __launch_bounds__(256)
void finalize_kernel(const float* __restrict__ ws, float* __restrict__ out_tail)
{
    __shared__ float sl[4], sc[4];
    const int t = threadIdx.x;
    float ls = 0.0f, cs = 0.0f;
#pragma unroll
    for (int i = 0; i < 8; ++i) {
        ls += ws[t + 256 * i];
        cs += ws[2048 + t + 256 * i];
    }
#pragma unroll
    for (int off = 32; off > 0; off >>= 1) {
        ls += __shfl_down(ls, off, 64);
        cs += __shfl_down(cs, off, 64);
    }
    if ((t & 63) == 0) { sl[t >> 6] = ls; sc[t >> 6] = cs; }
    __syncthreads();
    if (t == 0) {
        const float L = sl[0] + sl[1] + sl[2] + sl[3];
        const float C = sc[0] + sc[1] + sc[2] + sc[3];
        const float inv = 1.0f / (float)((size_t)BB * TT);
        out_tail[0] = C * inv;   // accuracy
        out_tail[1] = L * inv;   // loss
    }
}

extern "C" void kernel_launch(void* const* d_in, const int* in_sizes, int n_in,
                              void* d_out, int out_size, void* d_ws, size_t ws_size,
                              hipStream_t stream)
{
    const int*   tok    = (const int*)  d_in[0];
    const float* labels = (const float*)d_in[1];
    // d_in[2] = mask (unused by reference math)
    const float* emb = (const float*)d_in[3];
    const float* W   = (const float*)d_in[4];
    const float* U   = (const float*)d_in[5];
    const float* bv  = (const float*)d_in[6];
    const float* Wo  = (const float*)d_in[7];
    const float* bo  = (const float*)d_in[8];

    float* out    = (float*)d_out;
    float* states = out;                                  // [B,T,10]
    float* probs  = out + (size_t)BB * TT * RR;           // [B,T,3]
    float* tail   = out + (size_t)BB * TT * (RR + LL);    // accuracy, loss
    float* ws     = (float*)d_ws;                         // 4096 floats used

    rnn_seq_kernel<<<512, 256, 0, stream>>>(tok, emb, W, U, bv, states);
    epilogue_kernel<<<2048, 256, 0, stream>>>(states, labels, Wo, bo, probs, ws);
    finalize_kernel<<<1, 256, 0, stream>>>(ws, tail);
}

// Round 18
// 49.278 us; speedup vs baseline: 1.4546x; 1.0073x over previous
//
#include <hip/hip_runtime.h>
#include <math.h>

// Problem constants
#define BB 16384
#define TT 99
#define RR 10
#define LL 3

// DPP cross-lane (VALU pipe):
// QP(v,j): every lane of a 4-lane quad gets quad-lane j's value.
// HMIR(v): mirror within each 8-lane half-row (lane g <-> 7-g).
#define QP(v, j) __int_as_float(__builtin_amdgcn_mov_dpp(                     \
    __float_as_int(v), (j) * 0x55, 0xF, 0xF, true))
#define HMIR(v)  __int_as_float(__builtin_amdgcn_mov_dpp(                     \
    __float_as_int(v), 0x141, 0xF, 0xF, true))

// tanh(x) = 1 - 2/(exp(2x)+1); exact limits at +-inf.
__device__ __forceinline__ float fast_tanh(float x) {
    float e = __expf(2.0f * x);
    return fmaf(-2.0f, __builtin_amdgcn_rcpf(e + 1.0f), 1.0f);
}

// One 32-step (or 3-step tail) section of the recurrence: pure register loop.
// TB/N compile-time -> store offsets fold into 13-bit immediates.
template <int TB, int N>
__device__ __forceinline__ void rnn_section(
    uint64_t wq, float& hoA, float& hoB,
    const float (&UA)[RR], const float (&UB)[RR],
    float cA1, float cA2, float cB1, float cB2,
    float* __restrict__ outA, float* __restrict__ outB)
{
#pragma unroll
    for (int u = 0; u < N; ++u) {
        const int sel = (int)(wq & 3);
        wq >>= 2;

        // gather full h: 11 DPP ops (VALU pipe, zero memory)
        float hg[RR];
        hg[0] = QP(hoA, 0); hg[1] = QP(hoA, 1);
        hg[2] = QP(hoA, 2); hg[3] = QP(hoA, 3);
        const float mr = HMIR(hoA);
        hg[4] = QP(mr, 0);  hg[5] = QP(mr, 1);
        hg[6] = QP(mr, 2);  hg[7] = QP(mr, 3);
        hg[8] = QP(hoB, 0); hg[9] = QP(hoB, 1);

        const bool is1 = (sel == 1);
        float aA0 = is1 ? cA1 : cA2, aB0 = is1 ? cB1 : cB2;
        float aA1 = 0.0f, aB1 = 0.0f;
#pragma unroll
        for (int i = 0; i < 5; ++i) {          // split chains: 2x5 FMA deep
            aA0 = fmaf(hg[i],     UA[i],     aA0);
            aA1 = fmaf(hg[5 + i], UA[5 + i], aA1);
            aB0 = fmaf(hg[i],     UB[i],     aB0);
            aB1 = fmaf(hg[5 + i], UB[5 + i], aB1);
        }
        const float hnA = fast_tanh(aA0 + aA1);
        const float hnB = fast_tanh(aB0 + aB1);
        if (sel != 0) { hoA = hnA; hoB = hnB; }   // Keras masking: carry h

        // direct stores, compile-time offsets (max (TB+u)*40B = 3920 < 4096)
        outA[(TB + u) * RR] = hoA;
        outB[(TB + u) * RR] = hoB;
    }
}

// ===================== K1: recurrence -> states (direct) =====================
// R18 (= R17 fixed): ZERO memory ops in the sequential loop. The per-step
// token ds_read_u8 (prefetched only ~115cy ahead of its ~120cy latency ->
// per-step lgkmcnt stall, the suspected 55% stall source) is replaced by
// 2-bit token codes packed into FOUR u64 REGISTERS at setup. Per step:
// sel = wq & 3; wq >>= 2. Grid 512x256 = 2048 waves = 8 waves/CU.
__global__ __launch_bounds__(256, 2)
void rnn_seq_kernel(const int* __restrict__ tok_ids,
                    const float* __restrict__ emb,
                    const float* __restrict__ W,
                    const float* __restrict__ U,
                    const float* __restrict__ bvec,
                    float* __restrict__ states_out)
{
    __shared__ unsigned char s_tk[4][8 * 100];   // 3.2 KB: token byte per (row,t)

    const int tid = threadIdx.x;
    const int w   = tid >> 6;
    const int l   = tid & 63;
    const int r8  = l >> 3;                   // row within wave (0..7)
    const int g   = l & 7;                    // unit slot (0..7)
    const int rowbase = blockIdx.x * 32 + w * 8;

    // ---- stage tokens (coalesced) ----
#pragma unroll
    for (int i = 0; i < 13; ++i) {
        const int p = l + 64 * i;
        if (p < 8 * TT) {
            const int r = p / TT;             // compile-time divisor
            s_tk[w][r * 100 + (p - r * TT)] =
                (unsigned char)tok_ids[(size_t)rowbase * TT + p];
        }
    }

    // ---- pack own row's 99 token codes into 4 u64 registers (2 bits/step) ----
    // (all 8 lanes of a group pack the same row -- redundant but parallel;
    //  same-wave DS ordering makes the staged bytes visible without barrier)
    const uint32_t* tp = reinterpret_cast<const uint32_t*>(&s_tk[w][r8 * 100]);
    uint64_t w0 = 0, w1 = 0, w2 = 0, w3 = 0;
#pragma unroll
    for (int t = 0; t < 32; ++t)
        w0 |= (uint64_t)((tp[t >> 2] >> (8 * (t & 3))) & 3) << (2 * t);
#pragma unroll
    for (int t = 32; t < 64; ++t)
        w1 |= (uint64_t)((tp[t >> 2] >> (8 * (t & 3))) & 3) << (2 * (t - 32));
#pragma unroll
    for (int t = 64; t < 96; ++t)
        w2 |= (uint64_t)((tp[t >> 2] >> (8 * (t & 3))) & 3) << (2 * (t - 64));
#pragma unroll
    for (int t = 96; t < 99; ++t)
        w3 |= (uint64_t)((tp[t >> 2] >> (8 * (t & 3))) & 3) << (2 * (t - 96));

    // ---- per-lane gather order (quad-dependent) + weight coefficients ----
    const int qpar = g >> 2;
    int ord[8];
#pragma unroll
    for (int j = 0; j < 4; ++j) {
        ord[j]     = qpar ? 4 + j : j;
        ord[4 + j] = qpar ? 3 - j : 7 - j;
    }
    const int jA = g;
    const int jB = ((g & 3) < 2) ? 8 + (g & 3) : 8;

    float UA[RR], UB[RR];
#pragma unroll
    for (int k2 = 0; k2 < 8; ++k2) {
        UA[k2] = U[ord[k2] * RR + jA];
        UB[k2] = U[ord[k2] * RR + jB];
    }
    UA[8] = U[8 * RR + jA]; UA[9] = U[9 * RR + jA];
    UB[8] = U[8 * RR + jB]; UB[9] = U[9 * RR + jB];

    float cA1 = bvec[jA], cA2 = cA1, cB1 = bvec[jB], cB2 = cB1;
#pragma unroll
    for (int i = 0; i < RR; ++i) {
        const float e1 = emb[RR + i];          // token-1 row
        const float e2 = emb[2 * RR + i];      // token-2 row
        const float wA = W[i * RR + jA];
        const float wB = W[i * RR + jB];
        cA1 = fmaf(e1, wA, cA1); cA2 = fmaf(e2, wA, cA2);
        cB1 = fmaf(e1, wB, cB1); cB2 = fmaf(e2, wB, cB2);
    }

    float hoA = 0.0f, hoB = 0.0f;
    float* outA = states_out + (size_t)(rowbase + r8) * (TT * RR) + jA;
    float* outB = states_out + (size_t)(rowbase + r8) * (TT * RR) + jB;

    rnn_section< 0, 32>(w0, hoA, hoB, UA, UB, cA1, cA2, cB1, cB2, outA, outB);
    rnn_section<32, 32>(w1, hoA, hoB, UA, UB, cA1, cA2, cB1, cB2, outA, outB);
    rnn_section<64, 32>(w2, hoA, hoB, UA, UB, cA1, cA2, cB1, cB2, outA, outB);
    rnn_section<96,  3>(w3, hoA, hoB, UA, UB, cA1, cA2, cB1, cB2, outA, outB);
}

// ===================== K2: epilogue (full occupancy) =====================
__global__ __launch_bounds__(256)
void epilogue_kernel(const float* __restrict__ states,
                     const float* __restrict__ labels,
                     const float* __restrict__ Wo,
                     const float* __restrict__ bo,
                     float* __restrict__ probs_out,
                     float* __restrict__ ws)
{
    const int NT     = BB * TT;               // 1,622,016
    const int tid    = blockIdx.x * 256 + threadIdx.x;
    const int stride = 2048 * 256;

    float Wc0[RR], Wc1[RR], Wc2[RR];
#pragma unroll
    for (int j = 0; j < RR; ++j) {
        Wc0[j] = Wo[j * LL + 0];
        Wc1[j] = Wo[j * LL + 1];
        Wc2[j] = Wo[j * LL + 2];
    }
    const float b0 = bo[0], b1 = bo[1], b2 = bo[2];

    float loss = 0.0f;
    int   corr = 0;

#pragma unroll 1
    for (int idx = tid; idx < NT; idx += stride) {
        const float* hp = states + (size_t)idx * RR;   // 8B-aligned (40B stride)
        float h[RR];
#pragma unroll
        for (int j = 0; j < RR; j += 2) {
            const float2 v = *reinterpret_cast<const float2*>(hp + j);
            h[j] = v.x; h[j + 1] = v.y;
        }
        const float la1 = labels[(size_t)idx * LL + 1];
        const float la2 = labels[(size_t)idx * LL + 2];
        const int   y   = (la1 > 0.5f) ? 1 : ((la2 > 0.5f) ? 2 : 0);

        float l0 = b0, l1 = b1, l2 = b2;
#pragma unroll
        for (int j = 0; j < RR; ++j) {
            l0 = fmaf(h[j], Wc0[j], l0);
            l1 = fmaf(h[j], Wc1[j], l1);
            l2 = fmaf(h[j], Wc2[j], l2);
        }
        const float e0 = __expf(l0), e1 = __expf(l1), e2 = __expf(l2);
        const float S  = e0 + e1 + e2;
        const float rs = __builtin_amdgcn_rcpf(S);
        probs_out[(size_t)idx * LL + 0] = e0 * rs;
        probs_out[(size_t)idx * LL + 1] = e1 * rs;
        probs_out[(size_t)idx * LL + 2] = e2 * rs;

        // loss: -log(clip(p_y, 1e-7, 1)) == min(logS - l_y, -log(1e-7))
        const float ly = (y == 0) ? l0 : ((y == 1) ? l1 : l2);
        loss += fminf(__logf(S) - ly, 16.11809565f);

        // accuracy: argmax(logits) == argmax(probs) (monotonic, same ties)
        int ap = 0; float pm = l0;
        if (l1 > pm) { ap = 1; pm = l1; }
        if (l2 > pm) { ap = 2; }
        corr += (ap == y) ? 1 : 0;
    }

    __shared__ float sl[4], sc[4];
    float ls = loss, cs = (float)corr;
#pragma unroll
    for (int off = 32; off > 0; off >>= 1) {
        ls += __shfl_down(ls, off, 64);
        cs += __shfl_down(cs, off, 64);
    }
    if ((threadIdx.x & 63) == 0) { sl[threadIdx.x >> 6] = ls; sc[threadIdx.x >> 6] = cs; }
    __syncthreads();
    if (threadIdx.x == 0) {
        ws[blockIdx.x]        = sl[0] + sl[1] + sl[2] + sl[3];
        ws[2048 + blockIdx.x] = sc[0] + sc[1] + sc[2] + sc[3];
    }
}

__global__ __launch_bounds__(256)
void finalize_kernel(const float* __restrict__ ws, float* __restrict__ out_tail)
{
    __shared__ float sl[4], sc[4];
    const int t = threadIdx.x;
    float ls = 0.0f, cs = 0.0f;
#pragma unroll
    for (int i = 0; i < 8; ++i) {
        ls += ws[t + 256 * i];
        cs += ws[2048 + t + 256 * i];
    }
#pragma unroll
    for (int off = 32; off > 0; off >>= 1) {
        ls += __shfl_down(ls, off, 64);
        cs += __shfl_down(cs, off, 64);
    }
    if ((t & 63) == 0) { sl[t >> 6] = ls; sc[t >> 6] = cs; }
    __syncthreads();
    if (t == 0) {
        const float L = sl[0] + sl[1] + sl[2] + sl[3];
        const float C = sc[0] + sc[1] + sc[2] + sc[3];
        const float inv = 1.0f / (float)((size_t)BB * TT);
        out_tail[0] = C * inv;   // accuracy
        out_tail[1] = L * inv;   // loss
    }
}

extern "C" void kernel_launch(void* const* d_in, const int* in_sizes, int n_in,
                              void* d_out, int out_size, void* d_ws, size_t ws_size,
                              hipStream_t stream)
{
    const int*   tok    = (const int*)  d_in[0];
    const float* labels = (const float*)d_in[1];
    // d_in[2] = mask (unused by reference math)
    const float* emb = (const float*)d_in[3];
    const float* W   = (const float*)d_in[4];
    const float* U   = (const float*)d_in[5];
    const float* bv  = (const float*)d_in[6];
    const float* Wo  = (const float*)d_in[7];
    const float* bo  = (const float*)d_in[8];

    float* out    = (float*)d_out;
    float* states = out;                                  // [B,T,10]
    float* probs  = out + (size_t)BB * TT * RR;           // [B,T,3]
    float* tail   = out + (size_t)BB * TT * (RR + LL);    // accuracy, loss
    float* ws     = (float*)d_ws;                         // 4096 floats used

    rnn_seq_kernel<<<512, 256, 0, stream>>>(tok, emb, W, U, bv, states);
    epilogue_kernel<<<2048, 256, 0, stream>>>(states, labels, Wo, bo, probs, ws);
    finalize_kernel<<<1, 256, 0, stream>>>(ws, tail);
}